// Round 2
// baseline (1647.496 us; speedup 1.0000x reference)
//
#include <hip/hip_runtime.h>
#include <hip/hip_bf16.h>

#define T_TOK 16384
#define DM 1024
#define DF 4096
#define NE 8

typedef __attribute__((ext_vector_type(8))) short short8;
typedef __attribute__((ext_vector_type(4))) float f32x4;

__device__ __forceinline__ void gload_lds16(const void* g, void* l) {
  __builtin_amdgcn_global_load_lds((const __attribute__((address_space(1))) void*)g,
                                   (__attribute__((address_space(3))) void*)l, 16, 0, 0);
}

// ---------------- x -> bf16 ----------------
struct alignas(16) BF8 { __hip_bfloat16 v[8]; };
struct alignas(8) BF4 { __hip_bfloat16 v[4]; };

__global__ __launch_bounds__(256) void cvt_x_kernel(const float* __restrict__ x,
                                                    __hip_bfloat16* __restrict__ xb) {
  size_t i = (size_t)blockIdx.x * 256 + threadIdx.x;
  const float4* s = (const float4*)x;
  float4 a = s[2 * i], b = s[2 * i + 1];
  BF8 o;
  o.v[0] = __float2bfloat16(a.x); o.v[1] = __float2bfloat16(a.y);
  o.v[2] = __float2bfloat16(a.z); o.v[3] = __float2bfloat16(a.w);
  o.v[4] = __float2bfloat16(b.x); o.v[5] = __float2bfloat16(b.y);
  o.v[6] = __float2bfloat16(b.z); o.v[7] = __float2bfloat16(b.w);
  ((BF8*)xb)[i] = o;
}

// ---------------- transpose + convert: src f32 [B][R][C] -> dst bf16 [B][C][R] ----------------
// 64x64 tile, float4 loads (1KB/wave), ushort4 stores.
__global__ __launch_bounds__(256) void tcvt_kernel(const float* __restrict__ src,
                                                   __hip_bfloat16* __restrict__ dst,
                                                   int R, int C) {
  __shared__ float t[64][65];
  const int b = blockIdx.z;
  const int r0 = blockIdx.y * 64, c0 = blockIdx.x * 64;
  const int tid = threadIdx.x;
  const int lr = tid >> 4;          // 0..15
  const int lc = (tid & 15) * 4;    // 0..60
  const float* s = src + ((size_t)b * R + r0) * C + c0;
#pragma unroll
  for (int rr = 0; rr < 64; rr += 16) {
    float4 v = *(const float4*)(s + (size_t)(lr + rr) * C + lc);
    t[lr + rr][lc] = v.x; t[lr + rr][lc + 1] = v.y;
    t[lr + rr][lc + 2] = v.z; t[lr + rr][lc + 3] = v.w;
  }
  __syncthreads();
  __hip_bfloat16* d = dst + ((size_t)b * C + c0) * R + r0;
  const int wc = tid >> 4;          // 0..15
  const int wr = (tid & 15) * 4;    // 0..60
#pragma unroll
  for (int cc = 0; cc < 64; cc += 16) {
    BF4 o;
#pragma unroll
    for (int j = 0; j < 4; j++) o.v[j] = __float2bfloat16(t[wr + j][wc + cc]);
    *(BF4*)(d + (size_t)(wc + cc) * R + wr) = o;
  }
}

// ---------------- router: logits, softmax, top-2, counts ----------------
__global__ __launch_bounds__(256) void router_kernel(const float* __restrict__ x,
                                                     const float* __restrict__ wr,
                                                     int* __restrict__ counts,
                                                     int* __restrict__ topk_i,
                                                     float* __restrict__ topk_w) {
  __shared__ float4 wl[8 * 257];
  int tid = threadIdx.x;
  for (int i = tid; i < 2048; i += 256) {
    int e = i >> 8, c = i & 255;
    wl[e * 257 + c] = ((const float4*)wr)[i];
  }
  __syncthreads();
  int tok = blockIdx.x * 32 + (tid >> 3);
  int e = tid & 7;
  const float4* xr = (const float4*)(x + (size_t)tok * DM);
  float s = 0.f;
  for (int c = 0; c < 256; c++) {
    float4 a = xr[c];
    float4 b = wl[e * 257 + c];
    s += a.x * b.x + a.y * b.y + a.z * b.z + a.w * b.w;
  }
  int lane = tid & 63;
  int base = lane & ~7;
  float l[8];
#pragma unroll
  for (int j = 0; j < 8; j++) l[j] = __shfl(s, base + j, 64);
  float mx = l[0];
#pragma unroll
  for (int j = 1; j < 8; j++) mx = fmaxf(mx, l[j]);
  float p[8], sum = 0.f;
#pragma unroll
  for (int j = 0; j < 8; j++) { p[j] = __expf(l[j] - mx); sum += p[j]; }
  int i1 = 0;
#pragma unroll
  for (int j = 1; j < 8; j++) if (l[j] > l[i1]) i1 = j;
  int i2 = (i1 == 0) ? 1 : 0;
#pragma unroll
  for (int j = 0; j < 8; j++) if (j != i1 && l[j] > l[i2]) i2 = j;
  float p1 = p[i1] / sum, p2 = p[i2] / sum;
  float inv = 1.0f / (p1 + p2);
  if ((tid & 7) == 0) {
    topk_i[2 * tok] = i1; topk_i[2 * tok + 1] = i2;
    topk_w[2 * tok] = p1 * inv; topk_w[2 * tok + 1] = p2 * inv;
    atomicAdd(&counts[i1], 1);
    atomicAdd(&counts[i2], 1);
  }
}

__global__ void prefix_kernel(const int* __restrict__ counts, int* __restrict__ offsets,
                              int* __restrict__ cursors) {
  int t = threadIdx.x;
  if (t < NE) cursors[t] = 0;
  if (t == 0) {
    int run = 0;
    for (int e = 0; e < NE; e++) { offsets[e] = run; run += counts[e]; }
  }
}

__global__ __launch_bounds__(256) void scatter_kernel(const int* __restrict__ topk_i,
                                                      const float* __restrict__ topk_w,
                                                      const int* __restrict__ offsets,
                                                      int* __restrict__ cursors,
                                                      int* __restrict__ tok_list,
                                                      float* __restrict__ wt_list) {
  int t = blockIdx.x * 256 + threadIdx.x;
  if (t >= T_TOK) return;
#pragma unroll
  for (int k = 0; k < 2; k++) {
    int e = topk_i[2 * t + k];
    int pos = atomicAdd(&cursors[e], 1);
    int slot = offsets[e] + pos;
    tok_list[slot] = t;
    wt_list[slot] = topk_w[2 * t + k];
  }
}

// ---------------- GEMM1: h[slot] = gelu(x[tok] @ w1[e])  tile 128M x 256N, BK=32 ----------------
__global__ __launch_bounds__(256, 2) void gemm1_kernel(
    const __hip_bfloat16* __restrict__ xb, const __hip_bfloat16* __restrict__ w1bt,
    const int* __restrict__ tok_list, const int* __restrict__ counts,
    const int* __restrict__ offsets, __hip_bfloat16* __restrict__ h) {
  const int e = blockIdx.y >> 7;
  const int mb = blockIdx.y & 127;
  const int cnt = counts[e];
  const int m0 = mb * 128;
  if (m0 >= cnt) return;
  const int rem = cnt - m0;
  const int seg = offsets[e];
  const int nb = blockIdx.x;  // 0..15

  __shared__ __align__(16) __hip_bfloat16 As[128 * 32];   // 8 KB
  __shared__ __align__(16) __hip_bfloat16 Bs[256 * 32];   // 16 KB

  const int tid = threadIdx.x;
  const __hip_bfloat16* wB = w1bt + ((size_t)e * DF + (size_t)nb * 256) * DM;

  const __hip_bfloat16* gA[2]; char* lA[2];
  const __hip_bfloat16* gB[4]; char* lB[4];
#pragma unroll
  for (int i = 0; i < 2; i++) {
    int idx = tid + i * 256;
    int row = idx >> 2;
    int gg = (idx & 3) ^ ((row >> 1) & 3);
    int r = row < rem ? row : rem - 1;
    int tok = tok_list[seg + m0 + r];
    gA[i] = xb + (size_t)tok * DM + gg * 8;
    lA[i] = (char*)As + idx * 16;
  }
#pragma unroll
  for (int i = 0; i < 4; i++) {
    int idx = tid + i * 256;
    int row = idx >> 2;
    int gg = (idx & 3) ^ ((row >> 1) & 3);
    gB[i] = wB + (size_t)row * DM + gg * 8;
    lB[i] = (char*)Bs + idx * 16;
  }

  const int lane = tid & 63;
  const int wv = tid >> 6;
  const int wm = (wv >> 1) * 64, wn = (wv & 1) * 128;
  const int m16 = lane & 15, q = lane >> 4;

  const char* pa[4]; const char* pb[8];
#pragma unroll
  for (int mt = 0; mt < 4; mt++) {
    int row = wm + mt * 16 + m16;
    pa[mt] = (const char*)As + row * 64 + ((q ^ ((row >> 1) & 3)) * 16);
  }
#pragma unroll
  for (int nt = 0; nt < 8; nt++) {
    int row = wn + nt * 16 + m16;
    pb[nt] = (const char*)Bs + row * 64 + ((q ^ ((row >> 1) & 3)) * 16);
  }

  f32x4 acc[4][8] = {};

  for (int k0 = 0; k0 < DM; k0 += 32) {
    __syncthreads();
#pragma unroll
    for (int i = 0; i < 2; i++) gload_lds16(gA[i] + k0, lA[i]);
#pragma unroll
    for (int i = 0; i < 4; i++) gload_lds16(gB[i] + k0, lB[i]);
    __syncthreads();
    short8 av[4], bv[8];
#pragma unroll
    for (int mt = 0; mt < 4; mt++) av[mt] = *(const short8*)pa[mt];
#pragma unroll
    for (int nt = 0; nt < 8; nt++) bv[nt] = *(const short8*)pb[nt];
#pragma unroll
    for (int mt = 0; mt < 4; mt++)
#pragma unroll
      for (int nt = 0; nt < 8; nt++)
        acc[mt][nt] = __builtin_amdgcn_mfma_f32_16x16x32_bf16(av[mt], bv[nt], acc[mt][nt], 0, 0, 0);
  }

#pragma unroll
  for (int mt = 0; mt < 4; mt++) {
#pragma unroll
    for (int r = 0; r < 4; r++) {
      const int row = wm + mt * 16 + q * 4 + r;
      if (row < rem) {
        __hip_bfloat16* hr = h + (size_t)(seg + m0 + row) * DF + nb * 256 + wn + m16;
#pragma unroll
        for (int nt = 0; nt < 8; nt++) {
          float v = acc[mt][nt][r];
          v = 0.5f * v * (1.0f + erff(v * 0.70710678118654752f));
          hr[nt * 16] = __float2bfloat16(v);
        }
      }
    }
  }
}

// ---------------- GEMM2: out[tok] += wt * (h[slot] @ w2[e])  tile 128M x 256N, BK=32 ----------------
__global__ __launch_bounds__(256, 2) void gemm2_kernel(
    const __hip_bfloat16* __restrict__ h, const __hip_bfloat16* __restrict__ w2bt,
    const int* __restrict__ tok_list, const float* __restrict__ wt_list,
    const int* __restrict__ counts, const int* __restrict__ offsets,
    float* __restrict__ out) {
  const int e = blockIdx.y >> 7;
  const int mb = blockIdx.y & 127;
  const int cnt = counts[e];
  const int m0 = mb * 128;
  if (m0 >= cnt) return;
  const int rem = cnt - m0;
  const int seg = offsets[e];
  const int nb = blockIdx.x;  // 0..3

  __shared__ __align__(16) __hip_bfloat16 As[128 * 32];
  __shared__ __align__(16) __hip_bfloat16 Bs[256 * 32];

  const int tid = threadIdx.x;
  const __hip_bfloat16* wB = w2bt + ((size_t)e * DM + (size_t)nb * 256) * DF;

  const __hip_bfloat16* gA[2]; char* lA[2];
  const __hip_bfloat16* gB[4]; char* lB[4];
#pragma unroll
  for (int i = 0; i < 2; i++) {
    int idx = tid + i * 256;
    int row = idx >> 2;
    int gg = (idx & 3) ^ ((row >> 1) & 3);
    int r = row < rem ? row : rem - 1;
    gA[i] = h + (size_t)(seg + m0 + r) * DF + gg * 8;
    lA[i] = (char*)As + idx * 16;
  }
#pragma unroll
  for (int i = 0; i < 4; i++) {
    int idx = tid + i * 256;
    int row = idx >> 2;
    int gg = (idx & 3) ^ ((row >> 1) & 3);
    gB[i] = wB + (size_t)row * DF + gg * 8;
    lB[i] = (char*)Bs + idx * 16;
  }

  const int lane = tid & 63;
  const int wv = tid >> 6;
  const int wm = (wv >> 1) * 64, wn = (wv & 1) * 128;
  const int m16 = lane & 15, q = lane >> 4;

  const char* pa[4]; const char* pb[8];
#pragma unroll
  for (int mt = 0; mt < 4; mt++) {
    int row = wm + mt * 16 + m16;
    pa[mt] = (const char*)As + row * 64 + ((q ^ ((row >> 1) & 3)) * 16);
  }
#pragma unroll
  for (int nt = 0; nt < 8; nt++) {
    int row = wn + nt * 16 + m16;
    pb[nt] = (const char*)Bs + row * 64 + ((q ^ ((row >> 1) & 3)) * 16);
  }

  f32x4 acc[4][8] = {};

  for (int k0 = 0; k0 < DF; k0 += 32) {
    __syncthreads();
#pragma unroll
    for (int i = 0; i < 2; i++) gload_lds16(gA[i] + k0, lA[i]);
#pragma unroll
    for (int i = 0; i < 4; i++) gload_lds16(gB[i] + k0, lB[i]);
    __syncthreads();
    short8 av[4], bv[8];
#pragma unroll
    for (int mt = 0; mt < 4; mt++) av[mt] = *(const short8*)pa[mt];
#pragma unroll
    for (int nt = 0; nt < 8; nt++) bv[nt] = *(const short8*)pb[nt];
#pragma unroll
    for (int mt = 0; mt < 4; mt++)
#pragma unroll
      for (int nt = 0; nt < 8; nt++)
        acc[mt][nt] = __builtin_amdgcn_mfma_f32_16x16x32_bf16(av[mt], bv[nt], acc[mt][nt], 0, 0, 0);
  }

#pragma unroll
  for (int mt = 0; mt < 4; mt++) {
#pragma unroll
    for (int r = 0; r < 4; r++) {
      const int row = wm + mt * 16 + q * 4 + r;
      if (row < rem) {
        const int slot = seg + m0 + row;
        const int tok = tok_list[slot];
        const float wt = wt_list[slot];
        float* orow = out + (size_t)tok * DM + nb * 256 + wn + m16;
#pragma unroll
        for (int nt = 0; nt < 8; nt++)
          atomicAdd(&orow[nt * 16], wt * acc[mt][nt][r]);
      }
    }
  }
}

extern "C" void kernel_launch(void* const* d_in, const int* in_sizes, int n_in,
                              void* d_out, int out_size, void* d_ws, size_t ws_size,
                              hipStream_t stream) {
  const float* x = (const float*)d_in[0];
  const float* wr = (const float*)d_in[1];
  const float* w1 = (const float*)d_in[2];
  const float* w2 = (const float*)d_in[3];
  float* out = (float*)d_out;

  char* p = (char*)d_ws;
  __hip_bfloat16* xb = (__hip_bfloat16*)p;   p += (size_t)T_TOK * DM * 2;
  __hip_bfloat16* w1bt = (__hip_bfloat16*)p; p += (size_t)NE * DM * DF * 2;
  __hip_bfloat16* w2bt = (__hip_bfloat16*)p; p += (size_t)NE * DF * DM * 2;
  __hip_bfloat16* h = (__hip_bfloat16*)p;    p += (size_t)2 * T_TOK * DF * 2;
  int* tok_list = (int*)p;   p += (size_t)2 * T_TOK * 4;
  float* wt_list = (float*)p; p += (size_t)2 * T_TOK * 4;
  int* topk_i = (int*)p;     p += (size_t)T_TOK * 2 * 4;
  float* topk_w = (float*)p; p += (size_t)T_TOK * 2 * 4;
  int* counts = (int*)p;     p += 32;
  int* offsets = (int*)p;    p += 32;
  int* cursors = (int*)p;    p += 32;

  hipMemsetAsync(counts, 0, 32, stream);
  hipMemsetAsync(out, 0, (size_t)T_TOK * DM * 4, stream);

  cvt_x_kernel<<<T_TOK * DM / 8 / 256, 256, 0, stream>>>(x, xb);
  tcvt_kernel<<<dim3(DF / 64, DM / 64, NE), 256, 0, stream>>>(w1, w1bt, DM, DF);
  tcvt_kernel<<<dim3(DM / 64, DF / 64, NE), 256, 0, stream>>>(w2, w2bt, DF, DM);
  router_kernel<<<T_TOK / 32, 256, 0, stream>>>(x, wr, counts, topk_i, topk_w);
  prefix_kernel<<<1, 64, 0, stream>>>(counts, offsets, cursors);
  scatter_kernel<<<T_TOK / 256, 256, 0, stream>>>(topk_i, topk_w, offsets, cursors,
                                                  tok_list, wt_list);
  gemm1_kernel<<<dim3(DF / 256, NE * 128), 256, 0, stream>>>(xb, w1bt, tok_list, counts,
                                                             offsets, h);
  gemm2_kernel<<<dim3(DM / 256, NE * 128), 256, 0, stream>>>(h, w2bt, tok_list, wt_list,
                                                             counts, offsets, out);
}

// Round 3
// 1199.552 us; speedup vs baseline: 1.3734x; 1.3734x over previous
//
#include <hip/hip_runtime.h>
#include <hip/hip_bf16.h>

#define T_TOK 16384
#define DM 1024
#define DF 4096
#define NE 8

typedef __attribute__((ext_vector_type(8))) short short8;
typedef __attribute__((ext_vector_type(4))) float f32x4;

__device__ __forceinline__ void gload_lds16(const void* g, void* l) {
  __builtin_amdgcn_global_load_lds((const __attribute__((address_space(1))) void*)g,
                                   (__attribute__((address_space(3))) void*)l, 16, 0, 0);
}

// cheap gelu: tanh-form, gelu(v) = v - v/(1+u), u = exp(v*(C1 + C2*v^2))
__device__ __forceinline__ float gelu_fast(float v) {
  float u = __expf(v * (1.59576912f + 0.07135481f * v * v));
  return v - v * __builtin_amdgcn_rcpf(1.0f + u);
}

// ---------------- x -> bf16 ----------------
struct alignas(16) BF8 { __hip_bfloat16 v[8]; };
struct alignas(8) BF4 { __hip_bfloat16 v[4]; };

__global__ __launch_bounds__(256) void cvt_x_kernel(const float* __restrict__ x,
                                                    __hip_bfloat16* __restrict__ xb) {
  size_t i = (size_t)blockIdx.x * 256 + threadIdx.x;
  const float4* s = (const float4*)x;
  float4 a = s[2 * i], b = s[2 * i + 1];
  BF8 o;
  o.v[0] = __float2bfloat16(a.x); o.v[1] = __float2bfloat16(a.y);
  o.v[2] = __float2bfloat16(a.z); o.v[3] = __float2bfloat16(a.w);
  o.v[4] = __float2bfloat16(b.x); o.v[5] = __float2bfloat16(b.y);
  o.v[6] = __float2bfloat16(b.z); o.v[7] = __float2bfloat16(b.w);
  ((BF8*)xb)[i] = o;
}

// ---------------- transpose + convert: src f32 [B][R][C] -> dst bf16 [B][C][R] ----------------
__global__ __launch_bounds__(256) void tcvt_kernel(const float* __restrict__ src,
                                                   __hip_bfloat16* __restrict__ dst,
                                                   int R, int C) {
  __shared__ float t[64][65];
  const int b = blockIdx.z;
  const int r0 = blockIdx.y * 64, c0 = blockIdx.x * 64;
  const int tid = threadIdx.x;
  const int lr = tid >> 4;
  const int lc = (tid & 15) * 4;
  const float* s = src + ((size_t)b * R + r0) * C + c0;
#pragma unroll
  for (int rr = 0; rr < 64; rr += 16) {
    float4 v = *(const float4*)(s + (size_t)(lr + rr) * C + lc);
    t[lr + rr][lc] = v.x; t[lr + rr][lc + 1] = v.y;
    t[lr + rr][lc + 2] = v.z; t[lr + rr][lc + 3] = v.w;
  }
  __syncthreads();
  __hip_bfloat16* d = dst + ((size_t)b * C + c0) * R + r0;
  const int wc = tid >> 4;
  const int wr = (tid & 15) * 4;
#pragma unroll
  for (int cc = 0; cc < 64; cc += 16) {
    BF4 o;
#pragma unroll
    for (int j = 0; j < 4; j++) o.v[j] = __float2bfloat16(t[wr + j][wc + cc]);
    *(BF4*)(d + (size_t)(wc + cc) * R + wr) = o;
  }
}

// ---------------- router: logits, softmax, top-2, LDS-privatized counts ----------------
__global__ __launch_bounds__(256) void router_kernel(const float* __restrict__ x,
                                                     const float* __restrict__ wr,
                                                     int* __restrict__ counts,
                                                     int* __restrict__ topk_i,
                                                     float* __restrict__ topk_w) {
  __shared__ float4 wl[8 * 257];
  __shared__ int lc[NE];
  int tid = threadIdx.x;
  if (tid < NE) lc[tid] = 0;
  for (int i = tid; i < 2048; i += 256) {
    int e = i >> 8, c = i & 255;
    wl[e * 257 + c] = ((const float4*)wr)[i];
  }
  __syncthreads();
  int tok = blockIdx.x * 32 + (tid >> 3);
  int e = tid & 7;
  const float4* xr = (const float4*)(x + (size_t)tok * DM);
  float s = 0.f;
  for (int c = 0; c < 256; c++) {
    float4 a = xr[c];
    float4 b = wl[e * 257 + c];
    s += a.x * b.x + a.y * b.y + a.z * b.z + a.w * b.w;
  }
  int lane = tid & 63;
  int base = lane & ~7;
  float l[8];
#pragma unroll
  for (int j = 0; j < 8; j++) l[j] = __shfl(s, base + j, 64);
  float mx = l[0];
#pragma unroll
  for (int j = 1; j < 8; j++) mx = fmaxf(mx, l[j]);
  float p[8], sum = 0.f;
#pragma unroll
  for (int j = 0; j < 8; j++) { p[j] = __expf(l[j] - mx); sum += p[j]; }
  int i1 = 0;
#pragma unroll
  for (int j = 1; j < 8; j++) if (l[j] > l[i1]) i1 = j;
  int i2 = (i1 == 0) ? 1 : 0;
#pragma unroll
  for (int j = 0; j < 8; j++) if (j != i1 && l[j] > l[i2]) i2 = j;
  float p1 = p[i1] / sum, p2 = p[i2] / sum;
  float inv = 1.0f / (p1 + p2);
  if ((tid & 7) == 0) {
    topk_i[2 * tok] = i1; topk_i[2 * tok + 1] = i2;
    topk_w[2 * tok] = p1 * inv; topk_w[2 * tok + 1] = p2 * inv;
    atomicAdd(&lc[i1], 1);
    atomicAdd(&lc[i2], 1);
  }
  __syncthreads();
  if (tid < NE) atomicAdd(&counts[tid], lc[tid]);
}

__global__ void prefix_kernel(const int* __restrict__ counts, int* __restrict__ offsets,
                              int* __restrict__ cursors) {
  int t = threadIdx.x;
  if (t < NE) cursors[t] = 0;
  if (t == 0) {
    int run = 0;
    for (int e = 0; e < NE; e++) { offsets[e] = run; run += counts[e]; }
  }
}

// ---------------- scatter: LDS-privatized range reservation ----------------
__global__ __launch_bounds__(256) void scatter_kernel(const int* __restrict__ topk_i,
                                                      const float* __restrict__ topk_w,
                                                      const int* __restrict__ offsets,
                                                      int* __restrict__ cursors,
                                                      int* __restrict__ tok_list,
                                                      float* __restrict__ wt_list) {
  __shared__ int lcnt[NE], lbase[NE];
  int tid = threadIdx.x;
  if (tid < NE) lcnt[tid] = 0;
  __syncthreads();
  int t = blockIdx.x * 256 + tid;
  int e0 = topk_i[2 * t], e1 = topk_i[2 * t + 1];
  float w0 = topk_w[2 * t], w1v = topk_w[2 * t + 1];
  int p0 = atomicAdd(&lcnt[e0], 1);
  int p1 = atomicAdd(&lcnt[e1], 1);
  __syncthreads();
  if (tid < NE) lbase[tid] = atomicAdd(&cursors[tid], lcnt[tid]);
  __syncthreads();
  int s0 = offsets[e0] + lbase[e0] + p0;
  int s1 = offsets[e1] + lbase[e1] + p1;
  tok_list[s0] = t; wt_list[s0] = w0;
  tok_list[s1] = t; wt_list[s1] = w1v;
}

// ---------------- GEMM1: h[slot] = gelu(x[tok] @ w1[e])  tile 128x128, BK=32 ----------------
__global__ __launch_bounds__(256, 3) void gemm1_kernel(
    const __hip_bfloat16* __restrict__ xb, const __hip_bfloat16* __restrict__ w1bt,
    const int* __restrict__ tok_list, const int* __restrict__ counts,
    const int* __restrict__ offsets, __hip_bfloat16* __restrict__ h) {
  const int e = blockIdx.y >> 7;
  const int mb = blockIdx.y & 127;
  const int cnt = counts[e];
  const int m0 = mb * 128;
  if (m0 >= cnt) return;
  const int rem = cnt - m0;
  const int seg = offsets[e];
  const int nb = blockIdx.x;  // 0..31

  __shared__ __align__(16) __hip_bfloat16 As[128 * 32];
  __shared__ __align__(16) __hip_bfloat16 Bs[128 * 32];

  const int tid = threadIdx.x;
  const __hip_bfloat16* wB = w1bt + ((size_t)e * DF + (size_t)nb * 128) * DM;

  const __hip_bfloat16* gA[2]; const __hip_bfloat16* gB[2];
  char* lA[2]; char* lB[2];
#pragma unroll
  for (int i = 0; i < 2; i++) {
    int idx = tid + i * 256;
    int row = idx >> 2;
    int gg = (idx & 3) ^ ((row >> 1) & 3);
    int r = row < rem ? row : rem - 1;
    int tok = tok_list[seg + m0 + r];
    gA[i] = xb + (size_t)tok * DM + gg * 8;
    gB[i] = wB + (size_t)row * DM + gg * 8;
    lA[i] = (char*)As + idx * 16;
    lB[i] = (char*)Bs + idx * 16;
  }

  const int lane = tid & 63;
  const int wv = tid >> 6;
  const int wm = (wv >> 1) * 64, wn = (wv & 1) * 64;
  const int m16 = lane & 15, q = lane >> 4;

  const char* pa[4]; const char* pb[4];
#pragma unroll
  for (int mt = 0; mt < 4; mt++) {
    int row = wm + mt * 16 + m16;
    pa[mt] = (const char*)As + row * 64 + ((q ^ ((row >> 1) & 3)) * 16);
  }
#pragma unroll
  for (int nt = 0; nt < 4; nt++) {
    int row = wn + nt * 16 + m16;
    pb[nt] = (const char*)Bs + row * 64 + ((q ^ ((row >> 1) & 3)) * 16);
  }

  f32x4 acc[4][4] = {};

  for (int k0 = 0; k0 < DM; k0 += 32) {
    __syncthreads();
#pragma unroll
    for (int i = 0; i < 2; i++) {
      gload_lds16(gA[i] + k0, lA[i]);
      gload_lds16(gB[i] + k0, lB[i]);
    }
    __syncthreads();
    short8 av[4], bv[4];
#pragma unroll
    for (int mt = 0; mt < 4; mt++) av[mt] = *(const short8*)pa[mt];
#pragma unroll
    for (int nt = 0; nt < 4; nt++) bv[nt] = *(const short8*)pb[nt];
#pragma unroll
    for (int mt = 0; mt < 4; mt++)
#pragma unroll
      for (int nt = 0; nt < 4; nt++)
        acc[mt][nt] = __builtin_amdgcn_mfma_f32_16x16x32_bf16(av[mt], bv[nt], acc[mt][nt], 0, 0, 0);
  }

#pragma unroll
  for (int mt = 0; mt < 4; mt++) {
#pragma unroll
    for (int r = 0; r < 4; r++) {
      const int row = wm + mt * 16 + q * 4 + r;
      if (row < rem) {
        __hip_bfloat16* hr = h + (size_t)(seg + m0 + row) * DF + nb * 128 + wn + m16;
#pragma unroll
        for (int nt = 0; nt < 4; nt++)
          hr[nt * 16] = __float2bfloat16(gelu_fast(acc[mt][nt][r]));
      }
    }
  }
}

// ---------------- GEMM2: out[tok] += wt * (h[slot] @ w2[e])  tile 128x128, BK=32 ----------------
__global__ __launch_bounds__(256, 3) void gemm2_kernel(
    const __hip_bfloat16* __restrict__ h, const __hip_bfloat16* __restrict__ w2bt,
    const int* __restrict__ tok_list, const float* __restrict__ wt_list,
    const int* __restrict__ counts, const int* __restrict__ offsets,
    float* __restrict__ out) {
  const int e = blockIdx.y >> 7;
  const int mb = blockIdx.y & 127;
  const int cnt = counts[e];
  const int m0 = mb * 128;
  if (m0 >= cnt) return;
  const int rem = cnt - m0;
  const int seg = offsets[e];
  const int nb = blockIdx.x;  // 0..7

  __shared__ __align__(16) __hip_bfloat16 As[128 * 32];
  __shared__ __align__(16) __hip_bfloat16 Bs[128 * 32];

  const int tid = threadIdx.x;
  const __hip_bfloat16* wB = w2bt + ((size_t)e * DM + (size_t)nb * 128) * DF;

  const __hip_bfloat16* gA[2]; const __hip_bfloat16* gB[2];
  char* lA[2]; char* lB[2];
#pragma unroll
  for (int i = 0; i < 2; i++) {
    int idx = tid + i * 256;
    int row = idx >> 2;
    int gg = (idx & 3) ^ ((row >> 1) & 3);
    int r = row < rem ? row : rem - 1;
    gA[i] = h + (size_t)(seg + m0 + r) * DF + gg * 8;
    gB[i] = wB + (size_t)row * DF + gg * 8;
    lA[i] = (char*)As + idx * 16;
    lB[i] = (char*)Bs + idx * 16;
  }

  const int lane = tid & 63;
  const int wv = tid >> 6;
  const int wm = (wv >> 1) * 64, wn = (wv & 1) * 64;
  const int m16 = lane & 15, q = lane >> 4;

  const char* pa[4]; const char* pb[4];
#pragma unroll
  for (int mt = 0; mt < 4; mt++) {
    int row = wm + mt * 16 + m16;
    pa[mt] = (const char*)As + row * 64 + ((q ^ ((row >> 1) & 3)) * 16);
  }
#pragma unroll
  for (int nt = 0; nt < 4; nt++) {
    int row = wn + nt * 16 + m16;
    pb[nt] = (const char*)Bs + row * 64 + ((q ^ ((row >> 1) & 3)) * 16);
  }

  f32x4 acc[4][4] = {};

  for (int k0 = 0; k0 < DF; k0 += 32) {
    __syncthreads();
#pragma unroll
    for (int i = 0; i < 2; i++) {
      gload_lds16(gA[i] + k0, lA[i]);
      gload_lds16(gB[i] + k0, lB[i]);
    }
    __syncthreads();
    short8 av[4], bv[4];
#pragma unroll
    for (int mt = 0; mt < 4; mt++) av[mt] = *(const short8*)pa[mt];
#pragma unroll
    for (int nt = 0; nt < 4; nt++) bv[nt] = *(const short8*)pb[nt];
#pragma unroll
    for (int mt = 0; mt < 4; mt++)
#pragma unroll
      for (int nt = 0; nt < 4; nt++)
        acc[mt][nt] = __builtin_amdgcn_mfma_f32_16x16x32_bf16(av[mt], bv[nt], acc[mt][nt], 0, 0, 0);
  }

#pragma unroll
  for (int mt = 0; mt < 4; mt++) {
#pragma unroll
    for (int r = 0; r < 4; r++) {
      const int row = wm + mt * 16 + q * 4 + r;
      if (row < rem) {
        const int slot = seg + m0 + row;
        const int tok = tok_list[slot];
        const float wt = wt_list[slot];
        float* orow = out + (size_t)tok * DM + nb * 128 + wn + m16;
#pragma unroll
        for (int nt = 0; nt < 4; nt++)
          atomicAdd(&orow[nt * 16], wt * acc[mt][nt][r]);
      }
    }
  }
}

extern "C" void kernel_launch(void* const* d_in, const int* in_sizes, int n_in,
                              void* d_out, int out_size, void* d_ws, size_t ws_size,
                              hipStream_t stream) {
  const float* x = (const float*)d_in[0];
  const float* wr = (const float*)d_in[1];
  const float* w1 = (const float*)d_in[2];
  const float* w2 = (const float*)d_in[3];
  float* out = (float*)d_out;

  char* p = (char*)d_ws;
  __hip_bfloat16* xb = (__hip_bfloat16*)p;   p += (size_t)T_TOK * DM * 2;
  __hip_bfloat16* w1bt = (__hip_bfloat16*)p; p += (size_t)NE * DM * DF * 2;
  __hip_bfloat16* w2bt = (__hip_bfloat16*)p; p += (size_t)NE * DF * DM * 2;
  __hip_bfloat16* h = (__hip_bfloat16*)p;    p += (size_t)2 * T_TOK * DF * 2;
  int* tok_list = (int*)p;   p += (size_t)2 * T_TOK * 4;
  float* wt_list = (float*)p; p += (size_t)2 * T_TOK * 4;
  int* topk_i = (int*)p;     p += (size_t)T_TOK * 2 * 4;
  float* topk_w = (float*)p; p += (size_t)T_TOK * 2 * 4;
  int* counts = (int*)p;     p += 32;
  int* offsets = (int*)p;    p += 32;
  int* cursors = (int*)p;    p += 32;

  hipMemsetAsync(counts, 0, 32, stream);
  hipMemsetAsync(out, 0, (size_t)T_TOK * DM * 4, stream);

  cvt_x_kernel<<<T_TOK * DM / 8 / 256, 256, 0, stream>>>(x, xb);
  tcvt_kernel<<<dim3(DF / 64, DM / 64, NE), 256, 0, stream>>>(w1, w1bt, DM, DF);
  tcvt_kernel<<<dim3(DM / 64, DF / 64, NE), 256, 0, stream>>>(w2, w2bt, DF, DM);
  router_kernel<<<T_TOK / 32, 256, 0, stream>>>(x, wr, counts, topk_i, topk_w);
  prefix_kernel<<<1, 64, 0, stream>>>(counts, offsets, cursors);
  scatter_kernel<<<T_TOK / 256, 256, 0, stream>>>(topk_i, topk_w, offsets, cursors,
                                                  tok_list, wt_list);
  gemm1_kernel<<<dim3(DF / 128, NE * 128), 256, 0, stream>>>(xb, w1bt, tok_list, counts,
                                                             offsets, h);
  gemm2_kernel<<<dim3(DM / 128, NE * 128), 256, 0, stream>>>(h, w2bt, tok_list, wt_list,
                                                             counts, offsets, out);
}